// Round 1
// baseline (531.441 us; speedup 1.0000x reference)
//
#include <hip/hip_runtime.h>
#include <math.h>

// Problem shape (fixed by reference setup_inputs):
//   B=8, K=8, C=256, H=W=64 -> HW=4096 floats = 1024 float4 per (b,k,c) plane.
#define B_DIM 8
#define K_DIM 8
#define C_DIM 256
#define HW4   1024   // HW / 4
#define CHUNK 4      // HW4 / 256 threads

// One block per (b,c). 2048 blocks x 256 threads.
// Memory-bound: stream CR once (dot + norm), softmax over K in LDS,
// stream IR once (weighted sum), write out. CT cached in registers.
__global__ __launch_bounds__(256)
void dfs_mixer_fused(const float4* __restrict__ IR,
                     const float4* __restrict__ CR,
                     const float4* __restrict__ CT,
                     float4* __restrict__ out)
{
    const int bid = blockIdx.x;       // b*C + c
    const int b   = bid >> 8;         // / C_DIM
    const int c   = bid & 255;        // % C_DIM
    const int t   = threadIdx.x;

    const int ct_base = bid * HW4;    // max 2048*1024 = 2^21, int-safe

    // Cache this thread's slice of CT[b,c] (reused across all K).
    float4 ct[CHUNK];
#pragma unroll
    for (int i = 0; i < CHUNK; ++i)
        ct[i] = CT[ct_base + i * 256 + t];

    // Pass 1: per-k dot and sum-of-squares partials.
    float dot[K_DIM], ss[K_DIM];
#pragma unroll
    for (int k = 0; k < K_DIM; ++k) {
        const int cr_base = ((b * K_DIM + k) * C_DIM + c) * HW4;  // < 2^24, int-safe
        float d = 0.f, s = 0.f;
#pragma unroll
        for (int i = 0; i < CHUNK; ++i) {
            float4 cr = CR[cr_base + i * 256 + t];
            d += ct[i].x * cr.x + ct[i].y * cr.y + ct[i].z * cr.z + ct[i].w * cr.w;
            s += cr.x * cr.x + cr.y * cr.y + cr.z * cr.z + cr.w * cr.w;
        }
        dot[k] = d; ss[k] = s;
    }

    // Wave(64)-level butterfly reduction for all 16 partials.
#pragma unroll
    for (int k = 0; k < K_DIM; ++k) {
#pragma unroll
        for (int off = 32; off >= 1; off >>= 1) {
            dot[k] += __shfl_xor(dot[k], off, 64);
            ss[k]  += __shfl_xor(ss[k],  off, 64);
        }
    }

    // Cross-wave reduction (4 waves) + softmax on thread 0, broadcast via LDS.
    __shared__ float red_d[4][K_DIM];
    __shared__ float red_s[4][K_DIM];
    __shared__ float wts[K_DIM];
    const int wave = t >> 6;
    const int lane = t & 63;
    if (lane == 0) {
#pragma unroll
        for (int k = 0; k < K_DIM; ++k) {
            red_d[wave][k] = dot[k];
            red_s[wave][k] = ss[k];
        }
    }
    __syncthreads();
    if (t == 0) {
        float sim[K_DIM];
        float m = -1e30f;
#pragma unroll
        for (int k = 0; k < K_DIM; ++k) {
            float d = red_d[0][k] + red_d[1][k] + red_d[2][k] + red_d[3][k];
            float s = red_s[0][k] + red_s[1][k] + red_s[2][k] + red_s[3][k];
            sim[k] = 2.0f * d / sqrtf(s);   // sim * 2.0 (softmax temperature)
            m = fmaxf(m, sim[k]);
        }
        float sum = 0.f;
#pragma unroll
        for (int k = 0; k < K_DIM; ++k) { sim[k] = expf(sim[k] - m); sum += sim[k]; }
        const float inv = 1.0f / sum;
#pragma unroll
        for (int k = 0; k < K_DIM; ++k) wts[k] = sim[k] * inv;
    }
    __syncthreads();

    float w[K_DIM];
#pragma unroll
    for (int k = 0; k < K_DIM; ++k) w[k] = wts[k];

    // Pass 2: weighted sum over IR, streamed once, coalesced float4.
#pragma unroll
    for (int i = 0; i < CHUNK; ++i) {
        float4 acc = make_float4(0.f, 0.f, 0.f, 0.f);
#pragma unroll
        for (int k = 0; k < K_DIM; ++k) {
            const int ir_base = ((b * K_DIM + k) * C_DIM + c) * HW4;
            float4 v = IR[ir_base + i * 256 + t];
            acc.x += w[k] * v.x;
            acc.y += w[k] * v.y;
            acc.z += w[k] * v.z;
            acc.w += w[k] * v.w;
        }
        out[ct_base + i * 256 + t] = acc;
    }
}

extern "C" void kernel_launch(void* const* d_in, const int* in_sizes, int n_in,
                              void* d_out, int out_size, void* d_ws, size_t ws_size,
                              hipStream_t stream) {
    const float4* IR = (const float4*)d_in[0];  // [B,K,C,H,W] fp32
    const float4* CR = (const float4*)d_in[1];  // [B,K,C,H,W] fp32
    const float4* CT = (const float4*)d_in[2];  // [B,C,H,W]   fp32
    float4* out      = (float4*)d_out;          // [B,C,H,W]   fp32

    dfs_mixer_fused<<<B_DIM * C_DIM, 256, 0, stream>>>(IR, CR, CT, out);
}

// Round 2
// 524.389 us; speedup vs baseline: 1.0134x; 1.0134x over previous
//
#include <hip/hip_runtime.h>
#include <math.h>

// Shapes fixed by reference: B=8, K=8, C=256, H=W=64 -> HW=4096 = 1024 float4/plane.
#define B_DIM 8
#define K_DIM 8
#define C_DIM 256
#define HW4   1024   // float4 elements per (b,k,c) plane

// One block per (b,c): 2048 blocks x 1024 threads (16 waves).
// Pass 1: wave-pair (128 threads) per k computes dot<CT,CR> and ||CR||^2.
// Softmax over K in LDS. Pass 2: all 1024 threads stream IR, weighted sum.
__global__ __launch_bounds__(1024, 8)
void dfs_mixer_fused(const float4* __restrict__ IR,
                     const float4* __restrict__ CR,
                     const float4* __restrict__ CT,
                     float4* __restrict__ out)
{
    const int bid  = blockIdx.x;          // b*C + c
    const int b    = bid >> 8;
    const int c    = bid & 255;
    const int t    = threadIdx.x;         // 0..1023
    const int wave = t >> 6;              // 0..15
    const int lane = t & 63;

    const int ct_base = bid * HW4;        // CT / out plane base (float4 units)

    // ---- Pass 1: this wave-pair's k ----
    const int k  = wave >> 1;             // 2 waves per k
    const int li = ((wave & 1) << 6) | lane;   // 0..127 within the k-group
    const int cr_base = (b * (K_DIM * C_DIM) + k * C_DIM + c) * HW4;

    float d = 0.f, s = 0.f;
#pragma unroll
    for (int i = 0; i < 8; ++i) {         // 128 threads x 8 float4 = 1024 float4
        const int off = li + i * 128;
        float4 ctv = CT[ct_base + off];
        float4 crv = CR[cr_base + off];
        d = fmaf(ctv.x, crv.x, d); d = fmaf(ctv.y, crv.y, d);
        d = fmaf(ctv.z, crv.z, d); d = fmaf(ctv.w, crv.w, d);
        s = fmaf(crv.x, crv.x, s); s = fmaf(crv.y, crv.y, s);
        s = fmaf(crv.z, crv.z, s); s = fmaf(crv.w, crv.w, s);
    }

    // Wave butterfly (2 scalars x 6 steps = 12 shuffles).
#pragma unroll
    for (int off = 32; off >= 1; off >>= 1) {
        d += __shfl_xor(d, off, 64);
        s += __shfl_xor(s, off, 64);
    }

    __shared__ float red_d[16];
    __shared__ float red_s[16];
    __shared__ float simbuf[K_DIM];
    __shared__ float wts[K_DIM];
    if (lane == 0) { red_d[wave] = d; red_s[wave] = s; }
    __syncthreads();

    // Threads 0..7: combine the two wave-halves of k=t, compute sim.
    if (t < K_DIM) {
        float dd = red_d[2 * t] + red_d[2 * t + 1];
        float ss = red_s[2 * t] + red_s[2 * t + 1];
        simbuf[t] = 2.0f * dd / sqrtf(ss);     // sim * 2.0 temperature
    }
    __syncthreads();

    // Threads 0..7 each compute their own softmax weight (redundant, cheap).
    if (t < K_DIM) {
        float m = -1e30f;
#pragma unroll
        for (int j = 0; j < K_DIM; ++j) m = fmaxf(m, simbuf[j]);
        float sum = 0.f;
#pragma unroll
        for (int j = 0; j < K_DIM; ++j) sum += expf(simbuf[j] - m);
        wts[t] = expf(simbuf[t] - m) / sum;
    }
    __syncthreads();

    float w[K_DIM];
#pragma unroll
    for (int j = 0; j < K_DIM; ++j) w[j] = wts[j];

    // ---- Pass 2: weighted sum over IR, 1 float4 per thread ----
    const int plane0 = (b * (K_DIM * C_DIM) + c) * HW4 + t;  // k=0 plane
    float4 acc = make_float4(0.f, 0.f, 0.f, 0.f);
#pragma unroll
    for (int j = 0; j < K_DIM; ++j) {
        float4 v = IR[plane0 + j * (C_DIM * HW4)];
        acc.x = fmaf(w[j], v.x, acc.x);
        acc.y = fmaf(w[j], v.y, acc.y);
        acc.z = fmaf(w[j], v.z, acc.z);
        acc.w = fmaf(w[j], v.w, acc.w);
    }
    out[ct_base + t] = acc;
}

extern "C" void kernel_launch(void* const* d_in, const int* in_sizes, int n_in,
                              void* d_out, int out_size, void* d_ws, size_t ws_size,
                              hipStream_t stream) {
    const float4* IR = (const float4*)d_in[0];  // [B,K,C,H,W] fp32
    const float4* CR = (const float4*)d_in[1];  // [B,K,C,H,W] fp32
    const float4* CT = (const float4*)d_in[2];  // [B,C,H,W]   fp32
    float4* out      = (float4*)d_out;          // [B,C,H,W]   fp32

    dfs_mixer_fused<<<B_DIM * C_DIM, 1024, 0, stream>>>(IR, CR, CT, out);
}